// Round 5
// baseline (367.958 us; speedup 1.0000x reference)
//
#include <hip/hip_runtime.h>

typedef unsigned short u16;
typedef __attribute__((ext_vector_type(8))) short bf16x8_t;
typedef __attribute__((ext_vector_type(4))) float f32x4_t;
typedef __attribute__((ext_vector_type(16))) float f32x16_t;

__device__ __forceinline__ u16 f2bf(float x){
  union { float f; unsigned u; } v; v.f = x;
  unsigned r = v.u + 0x7FFFu + ((v.u >> 16) & 1u);
  return (u16)(r >> 16);
}
__device__ __forceinline__ float bf2f(u16 h){
  union { unsigned u; float f; } v; v.u = ((unsigned)h) << 16;
  return v.f;
}
// truncation-pack two f32 -> (bf16(a) | bf16(b)<<16); bias cancels in renormalization
__device__ __forceinline__ unsigned pack_hi16(float a, float b){
  union { float f; unsigned u; } x, y; x.f = a; y.f = b;
  return (x.u >> 16) | (y.u & 0xFFFF0000u);
}
// same pack via one v_perm_b32: dst bytes = {a.b2, a.b3, b.b2, b.b3}
__device__ __forceinline__ unsigned packp(float a, float b){
  union { float f; unsigned u; } x, y; x.f = a; y.f = b;
  return __builtin_amdgcn_perm(y.u, x.u, 0x07060302u);
}

// async global->LDS DMA, 16B/lane; data lands at base + lane*16.
__device__ __forceinline__ void gl2lds16(const u16* g, u16* l){
  __builtin_amdgcn_global_load_lds((const __attribute__((address_space(1))) void*)g,
                                   (__attribute__((address_space(3))) void*)l, 16, 0, 0);
}

// ---- X = [gene|expr] concat, split into hi/lo bf16. 8192 rows x 1024 cols ----
__global__ __launch_bounds__(256) void split_concat_kernel(
    const float* __restrict__ gene, const float* __restrict__ expr,
    u16* __restrict__ Xh, u16* __restrict__ Xl)
{
  size_t e = ((size_t)blockIdx.x * 256 + threadIdx.x) * 4;
  int row = (int)(e >> 10);
  int col = (int)(e & 1023);
  const float* src = (col < 512) ? (gene + (size_t)row * 512 + col)
                                 : (expr + (size_t)row * 512 + (col - 512));
  float4 v = *(const float4*)src;
  float a[4] = {v.x, v.y, v.z, v.w};
  u16 hs[4], ls[4];
#pragma unroll
  for (int i = 0; i < 4; i++){
    hs[i] = f2bf(a[i]);
    ls[i] = f2bf(a[i] - bf2f(hs[i]));
  }
  *(uint2*)(Xh + e) = make_uint2(hs[0] | ((unsigned)hs[1] << 16), hs[2] | ((unsigned)hs[3] << 16));
  *(uint2*)(Xl + e) = make_uint2(ls[0] | ((unsigned)ls[1] << 16), ls[2] | ((unsigned)ls[3] << 16));
}

// ---- all weight transposes in ONE launch. W [K][N] f32 -> Wt [N][K] bf16 (hi, optional lo)
__global__ __launch_bounds__(256) void transpose_all_kernel(
    const float* __restrict__ Wf, const float* __restrict__ Wq,
    const float* __restrict__ Wk, const float* __restrict__ Wv,
    const float* __restrict__ Wo,
    u16* __restrict__ Wfth, u16* __restrict__ Wftl,
    u16* __restrict__ Wqth, u16* __restrict__ Wkth,
    u16* __restrict__ Wvth, u16* __restrict__ Woth)
{
  __shared__ float t[64][65];
  int id = blockIdx.x;
  const float* W; u16* Th; u16* Tl; int K, kx, ny;
  if (id < 128){ W = Wf; Th = Wfth; Tl = Wftl; K = 1024; kx = id >> 3; ny = id & 7; }
  else {
    int tt = id - 128; int wi = tt >> 6; tt &= 63; kx = tt >> 3; ny = tt & 7; K = 512;
    W  = (wi == 0) ? Wq  : (wi == 1) ? Wk  : (wi == 2) ? Wv  : Wo;
    Th = (wi == 0) ? Wqth: (wi == 1) ? Wkth: (wi == 2) ? Wvth: Woth;
    Tl = nullptr;
  }
  int k0 = kx * 64, n0 = ny * 64;
  int tid = threadIdx.x;
  int r = tid >> 4;
  int c4 = (tid & 15) * 4;
#pragma unroll
  for (int p = 0; p < 4; p++){
    int k = p * 16 + r;
    float4 v = *(const float4*)(W + (size_t)(k0 + k) * 512 + n0 + c4);
    t[c4 + 0][k] = v.x; t[c4 + 1][k] = v.y; t[c4 + 2][k] = v.z; t[c4 + 3][k] = v.w;
  }
  __syncthreads();
#pragma unroll
  for (int p = 0; p < 4; p++){
    int n = p * 16 + r;
    u16 hs[4], ls[4];
#pragma unroll
    for (int i = 0; i < 4; i++){
      float x = t[n][c4 + i];
      hs[i] = f2bf(x);
      ls[i] = f2bf(x - bf2f(hs[i]));
    }
    size_t o = (size_t)(n0 + n) * K + k0 + c4;
    *(uint2*)(Th + o) = make_uint2(hs[0] | ((unsigned)hs[1] << 16), hs[2] | ((unsigned)hs[3] << 16));
    if (Tl)
      *(uint2*)(Tl + o) = make_uint2(ls[0] | ((unsigned)ls[1] << 16), ls[2] | ((unsigned)ls[3] << 16));
  }
}

// ---- GEMM, templated on split count and output mode ----
// C[M][512] = A[M][K] @ B[K][512] + bias ; B given transposed [512][K].
// SPLITS: 3 = aH*bH + aH*bL + aL*bH ; 2 = aH*bH + aL*bH ; 1 = aH*bH
// MODE: 0 = split bf16 out (o0=hi,o1=lo) ; 1 = bf16 row-major, scaled
//       2 = bf16 V^T per head [(b*8+h)*64+d][s] ; 3 = f32 row-major
// DUAL: blockIdx.y>=8 selects second (Bh1,bias1,outsec,sc1) set.
// BM=128 BN=64 BK=32; 256 thr = 4 waves (2x2 of 64x32); XOR-swizzled LDS granules.
template<int SPLITS, int MODE, int DUAL>
__global__ __launch_bounds__(256, 2) void gemm_kernel(
    const u16* __restrict__ Ah, const u16* __restrict__ Al, int lda,
    const u16* __restrict__ Bh0, const u16* __restrict__ Bl0,
    const u16* __restrict__ Bh1, int K,
    const float* __restrict__ bias0, const float* __restrict__ bias1,
    void* __restrict__ out0, void* __restrict__ out1, void* __restrict__ outsec,
    float sc0, float sc1)
{
  __shared__ __align__(16) u16 sAh[128 * 32];
  __shared__ __align__(16) u16 sAl[SPLITS >= 2 ? 128 * 32 : 8];
  __shared__ __align__(16) u16 sBh[64 * 32];
  __shared__ __align__(16) u16 sBl[SPLITS == 3 ? 64 * 32 : 8];
  int tid = threadIdx.x;
  int lane = tid & 63, w = tid >> 6, quad = lane >> 4, l15 = lane & 15;
  int wm = w & 1, wn = w >> 1;
  int m0 = blockIdx.x * 128;
  int side = DUAL ? (int)(blockIdx.y >> 3) : 0;
  int n0 = (DUAL ? (int)(blockIdx.y & 7) : (int)blockIdx.y) * 64;
  const u16* Bh = (DUAL && side) ? Bh1 : Bh0;
  const float* bias = (DUAL && side) ? bias1 : bias0;
  void* o0 = (DUAL && side) ? outsec : out0;
  float sc = (DUAL && side) ? sc1 : sc0;

  f32x4_t acc[4][2];
#pragma unroll
  for (int i = 0; i < 4; i++)
#pragma unroll
    for (int j = 0; j < 2; j++)
#pragma unroll
      for (int r = 0; r < 4; r++) acc[i][j][r] = 0.f;

  int lrow = lane >> 2;
  int swzS = ((lane >> 2) & 3) ^ ((lane >> 4) & 3);
  int gkq  = ((lane & 3) ^ swzS) * 8;
  const u16* pAh0 = Ah + (size_t)(m0 + w * 32 + lrow) * lda + gkq;
  const u16* pAh1 = Ah + (size_t)(m0 + w * 32 + 16 + lrow) * lda + gkq;
  const u16* pAl0 = (SPLITS >= 2) ? Al + (size_t)(m0 + w * 32 + lrow) * lda + gkq : nullptr;
  const u16* pAl1 = (SPLITS >= 2) ? Al + (size_t)(m0 + w * 32 + 16 + lrow) * lda + gkq : nullptr;
  const u16* pBh0 = Bh + (size_t)(n0 + w * 16 + lrow) * K + gkq;
  const u16* pBl0 = (SPLITS == 3) ? Bl0 + (size_t)(n0 + w * 16 + lrow) * K + gkq : nullptr;
  u16* dAh = sAh + w * 1024;
  u16* dAl = sAl + w * 1024;
  u16* dBh = sBh + w * 512;
  u16* dBl = sBl + w * 512;

  int pq = (quad ^ ((l15 & 3) ^ ((l15 >> 2) & 3))) * 8;

  for (int k0 = 0; k0 < K; k0 += 32){
    __syncthreads();
    gl2lds16(pAh0 + k0, dAh);
    gl2lds16(pAh1 + k0, dAh + 512);
    if constexpr (SPLITS >= 2){
      gl2lds16(pAl0 + k0, dAl);
      gl2lds16(pAl1 + k0, dAl + 512);
    }
    gl2lds16(pBh0 + k0, dBh);
    if constexpr (SPLITS == 3)
      gl2lds16(pBl0 + k0, dBl);
    __syncthreads();

    bf16x8_t aH[4], aL[4], bH[2], bL[2];
#pragma unroll
    for (int mi = 0; mi < 4; mi++){
      int ad = (wm * 64 + mi * 16 + l15) * 32 + pq;
      aH[mi] = *(const bf16x8_t*)&sAh[ad];
      if constexpr (SPLITS >= 2) aL[mi] = *(const bf16x8_t*)&sAl[ad];
    }
#pragma unroll
    for (int ni = 0; ni < 2; ni++){
      int bd = (wn * 32 + ni * 16 + l15) * 32 + pq;
      bH[ni] = *(const bf16x8_t*)&sBh[bd];
      if constexpr (SPLITS == 3) bL[ni] = *(const bf16x8_t*)&sBl[bd];
    }
#pragma unroll
    for (int mi = 0; mi < 4; mi++)
#pragma unroll
      for (int ni = 0; ni < 2; ni++){
        acc[mi][ni] = __builtin_amdgcn_mfma_f32_16x16x32_bf16(aH[mi], bH[ni], acc[mi][ni], 0, 0, 0);
        if constexpr (SPLITS == 3)
          acc[mi][ni] = __builtin_amdgcn_mfma_f32_16x16x32_bf16(aH[mi], bL[ni], acc[mi][ni], 0, 0, 0);
        if constexpr (SPLITS >= 2)
          acc[mi][ni] = __builtin_amdgcn_mfma_f32_16x16x32_bf16(aL[mi], bH[ni], acc[mi][ni], 0, 0, 0);
      }
  }

#pragma unroll
  for (int mi = 0; mi < 4; mi++)
#pragma unroll
    for (int ni = 0; ni < 2; ni++){
      int gn = n0 + wn * 32 + ni * 16 + l15;
      float bs = bias[gn];
      int gm0 = m0 + wm * 64 + mi * 16 + quad * 4;
#pragma unroll
      for (int r = 0; r < 4; r++){
        float v = acc[mi][ni][r] + bs;
        int gm = gm0 + r;
        if constexpr (MODE == 0){
          u16 hb = f2bf(v);
          ((u16*)o0)[(size_t)gm * 512 + gn] = hb;
          ((u16*)out1)[(size_t)gm * 512 + gn] = f2bf(v - bf2f(hb));
        } else if constexpr (MODE == 1){
          ((u16*)o0)[(size_t)gm * 512 + gn] = f2bf(v * sc);
        } else if constexpr (MODE == 2){
          int bb = gm >> 11, s = gm & 2047;
          int hh = gn >> 6, d = gn & 63;
          ((u16*)o0)[((size_t)((bb * 8 + hh) * 64 + d) << 11) + s] = f2bf(v);
        } else {
          ((float*)o0)[(size_t)gm * 512 + gn] = v;
        }
      }
    }
}

// ---- flash attention v6: v5's 32x32 register-P core + counted-vmcnt pipeline (T4).
// Same geometry/layout/numerics as v5 (verified): 4 waves = (wq q-half, wk kv-half),
// 2 heads/block, S^T = mfma(K,Q) with kv-permutation phi so post-softmax P sits in
// the PV B-operand layout lane-locally; K swizzle key = kv bits {4,3,0}, V key = d&7.
// NEW wait discipline: per phase, STAGE(next buf) [8 DMAs, pinned oldest] + load next
// M [4 dwordx4] -> COMPUTE(cur buf) -> s_waitcnt vmcnt(4) (drains exactly the 8 DMAs,
// M loads stay in flight across the barrier) -> raw s_barrier. One barrier/phase,
// zero full drains: DMA/M latency hides under a whole compute phase instead of being
// exposed 32x (the v1-v5 invariant ~85us was this exposed drain).
// Hazards: every wave vmcnt(4)-drains its own 8 DMAs pre-barrier => all tile-(t+1)
// DMAs complete before any wave passes barrier t; buf written only in the phase after
// its last read barrier. M ping-pong uses NAMED arrays MA/MB (no runtime indexing).
// grid (32,16): x = q-tile, y = b*4 + head-pair. 512 blocks = exactly 2/CU.
__global__ __launch_bounds__(256, 2) void flash_kernel(
    const u16* __restrict__ Qh, const u16* __restrict__ Kh,
    const u16* __restrict__ Vt, const float* __restrict__ Mm,
    u16* __restrict__ Oh)
{
  __shared__ __align__(16) u16 sAll[2][16384];  // [buf][ K: 2h x 4096 | V: 2h x 4096 ]
  int tid = threadIdx.x, lane = tid & 63, w = tid >> 6;
  int ql = lane & 31, hi = lane >> 5;
  int wq = w >> 1, wk = w & 1;
  int by = blockIdx.y, b = by >> 2, h0 = (by & 3) * 2;
  int q0 = blockIdx.x * 64;
  int q  = q0 + wq * 32 + ql;

  // Q B-frags: lane holds Q[q][d = dt*16 + hi*8 + j]
  const u16* qp = Qh + ((size_t)(b * 2048 + q)) * 512 + h0 * 64 + hi * 8;
  bf16x8_t qf[2][4];
#pragma unroll
  for (int h = 0; h < 2; h++)
#pragma unroll
    for (int dt = 0; dt < 4; dt++)
      qf[h][dt] = *(const bf16x8_t*)(qp + h * 64 + dt * 16);

  // staging pointers: wave (wq=head, wk=row-half); 4 K-calls + 4 V-calls, 8 rows each
  int srow = lane >> 3, c8 = lane & 7;
  const u16* gK[4]; const u16* gV[4];
#pragma unroll
  for (int c = 0; c < 4; c++){
    int kv = wk * 32 + c * 8 + srow;                       // physical row in 64-tile
    int skey = ((c >> 1) << 2) | ((c & 1) << 1) | (srow & 1);   // kv bits {4,3,0}
    gK[c] = Kh + ((size_t)(b * 2048 + kv)) * 512 + (h0 + wq) * 64 + ((c8 ^ skey) << 3);
    gV[c] = Vt + ((size_t)((b * 8 + h0 + wq) * 64 + kv)) * 2048 + ((c8 ^ srow) << 3);
  }
  int dO = wq * 4096 + wk * 2048;   // u16 offset (within K or V section)

  // QK read: A row m=ql -> LDS row kvL = wk*32 + phi(ql)
  int phi = ((ql >> 3) & 1) * 16 + ((ql >> 2) & 1) * 8 + (ql >> 4) * 4 + (ql & 3);
  int kvL = wk * 32 + phi;
  int skr = ((ql >> 3) & 1) * 4 + ((ql >> 2) & 1) * 2 + (ql & 1);  // = key(kvL)
  int kaddr[4];
#pragma unroll
  for (int dt = 0; dt < 4; dt++)
    kaddr[dt] = kvL * 64 + (((dt * 2 + hi) ^ skr) << 3);
  // PV read: A row = d_local = ql; col chunk = wk*4 + kt*2 + hi, key = d&7
  int vaddr[2][2];
#pragma unroll
  for (int dn = 0; dn < 2; dn++)
#pragma unroll
    for (int kt = 0; kt < 2; kt++)
      vaddr[dn][kt] = (dn * 32 + ql) * 64 + (((wk * 4 + kt * 2 + hi) ^ (ql & 7)) << 3);

  // M: element reg of S -> kv = wk*32 + hi*8 + (g&1)*16 + (g>>1)*4 + e
  const float* mp = Mm + (size_t)b * (2048 * 2048) + (size_t)q * 2048 + wk * 32 + hi * 8;
  const int og[4] = {0, 16, 4, 20};

  float lp[2] = {0.f, 0.f};
  f32x16_t Oc[2][2];
#pragma unroll
  for (int h = 0; h < 2; h++)
#pragma unroll
    for (int dn = 0; dn < 2; dn++)
#pragma unroll
      for (int r = 0; r < 16; r++) Oc[h][dn][r] = 0.f;

#define STAGE(B, KK) do {                                              \
    _Pragma("unroll")                                                  \
    for (int c = 0; c < 4; c++){                                       \
      gl2lds16(gK[c] + (size_t)(KK) * 512, &sAll[B][dO + c * 512]);    \
      gl2lds16(gV[c] + (KK),               &sAll[B][8192 + dO + c * 512]); \
    }                                                                  \
  } while (0)

#define COMPUTE(PH, MARR) do {                                          \
    const u16* kb_ = &sAll[PH][0];                                      \
    const u16* vb_ = &sAll[PH][8192];                                   \
    _Pragma("unroll")                                                   \
    for (int h = 0; h < 2; ++h){                                        \
      const u16* kbh = kb_ + h * 4096;                                  \
      const u16* vbh = vb_ + h * 4096;                                  \
      f32x16_t S;                                                       \
      _Pragma("unroll")                                                 \
      for (int r = 0; r < 16; r++) S[r] = 0.f;                          \
      __builtin_amdgcn_s_setprio(1);                                    \
      _Pragma("unroll")                                                 \
      for (int dt = 0; dt < 4; dt++){                                   \
        bf16x8_t kf = *(const bf16x8_t*)&kbh[kaddr[dt]];                \
        S = __builtin_amdgcn_mfma_f32_32x32x16_bf16(kf, qf[h][dt], S, 0, 0, 0); \
      }                                                                 \
      __builtin_amdgcn_s_setprio(0);                                    \
      float p[16];                                                      \
      _Pragma("unroll")                                                 \
      for (int g = 0; g < 4; g++)                                       \
        _Pragma("unroll")                                               \
        for (int e = 0; e < 4; e++){                                    \
          float m = MARR[g][e];                                         \
          float v = m * __builtin_amdgcn_exp2f(S[g * 4 + e] * m);       \
          lp[h] += v;                                                   \
          p[g * 4 + e] = v;                                             \
        }                                                               \
      __builtin_amdgcn_s_setprio(1);                                    \
      _Pragma("unroll")                                                 \
      for (int kt = 0; kt < 2; kt++){                                   \
        union { unsigned u[4]; bf16x8_t v8; } pb;                       \
        pb.u[0] = packp(p[kt * 4 + 0], p[kt * 4 + 1]);                  \
        pb.u[1] = packp(p[kt * 4 + 2], p[kt * 4 + 3]);                  \
        pb.u[2] = packp(p[kt * 4 + 8], p[kt * 4 + 9]);                  \
        pb.u[3] = packp(p[kt * 4 + 10], p[kt * 4 + 11]);                \
        _Pragma("unroll")                                               \
        for (int dn = 0; dn < 2; dn++){                                 \
          bf16x8_t vf = *(const bf16x8_t*)&vbh[vaddr[dn][kt]];          \
          Oc[h][dn] = __builtin_amdgcn_mfma_f32_32x32x16_bf16(vf, pb.v8, Oc[h][dn], 0, 0, 0); \
        }                                                               \
      }                                                                 \
      __builtin_amdgcn_s_setprio(0);                                    \
    }                                                                   \
  } while (0)

#define FENCE_BARRIER() do {                                            \
    __builtin_amdgcn_sched_barrier(0);                                  \
    __builtin_amdgcn_s_barrier();                                       \
    __builtin_amdgcn_sched_barrier(0);                                  \
  } while (0)

  f32x4_t MA[4], MB[4];

  // prologue: stage tile 0 -> buf0 (oldest), then M tile 0; drain DMAs only.
  STAGE(0, 0);
  __builtin_amdgcn_sched_barrier(0);
#pragma unroll
  for (int g = 0; g < 4; g++) MA[g] = *(const f32x4_t*)(mp + og[g]);
  asm volatile("s_waitcnt vmcnt(4)" ::: "memory");
  FENCE_BARRIER();

  for (int tt = 0; tt < 16; ++tt){
    {   // phase A: tile 2tt from buf0 with MA; stage tile 2tt+1 -> buf1, load MB
      int t = tt * 2;
      STAGE(1, (t + 1) * 64);
      __builtin_amdgcn_sched_barrier(0);
#pragma unroll
      for (int g = 0; g < 4; g++) MB[g] = *(const f32x4_t*)(mp + (t + 1) * 64 + og[g]);
      COMPUTE(0, MA);
      asm volatile("s_waitcnt vmcnt(4)" ::: "memory");
      FENCE_BARRIER();
    }
    {   // phase B: tile 2tt+1 from buf1 with MB; stage tile 2tt+2 -> buf0, load MA
      int t = tt * 2 + 1;
      bool nx = t < 31;
      if (nx){
        STAGE(0, (t + 1) * 64);
        __builtin_amdgcn_sched_barrier(0);
#pragma unroll
        for (int g = 0; g < 4; g++) MA[g] = *(const f32x4_t*)(mp + (t + 1) * 64 + og[g]);
      }
      COMPUTE(1, MB);
      if (nx) asm volatile("s_waitcnt vmcnt(4)" ::: "memory");
      else    asm volatile("s_waitcnt vmcnt(0)" ::: "memory");
      FENCE_BARRIER();
    }
  }
#undef STAGE
#undef COMPUTE
#undef FENCE_BARRIER

  // hi-halves hold disjoint kv -> sum across lane^32
  lp[0] += __shfl_xor(lp[0], 32);
  lp[1] += __shfl_xor(lp[1], 32);

  // reduce O and l across the two wk-halves via LDS (buffers dead: all waves passed
  // the final barrier, so compute reads of sAll are complete)
  float* red = (float*)&sAll[0][0];
  float* lpr = red + 8192;
  if (wk){
#pragma unroll
    for (int h = 0; h < 2; h++){
#pragma unroll
      for (int dn = 0; dn < 2; dn++)
#pragma unroll
        for (int rq = 0; rq < 4; rq++){
          f32x4_t o;
          o[0] = Oc[h][dn][rq * 4 + 0]; o[1] = Oc[h][dn][rq * 4 + 1];
          o[2] = Oc[h][dn][rq * 4 + 2]; o[3] = Oc[h][dn][rq * 4 + 3];
          *(f32x4_t*)&red[((((wq * 2 + h) * 2 + dn) * 4 + rq) * 64 + lane) * 4] = o;
        }
      lpr[(wq * 2 + h) * 64 + lane] = lp[h];
    }
  }
  __syncthreads();
  if (!wk){
#pragma unroll
    for (int h = 0; h < 2; h++){
      float li = lp[h] + lpr[(wq * 2 + h) * 64 + lane];
      float inv = 1.0f / li;
      size_t ob = ((size_t)(b * 2048 + q)) * 512 + (h0 + h) * 64;
#pragma unroll
      for (int dn = 0; dn < 2; dn++)
#pragma unroll
        for (int rq = 0; rq < 4; rq++){
          f32x4_t o = *(const f32x4_t*)&red[((((wq * 2 + h) * 2 + dn) * 4 + rq) * 64 + lane) * 4];
          float v0 = (Oc[h][dn][rq * 4 + 0] + o[0]) * inv;
          float v1 = (Oc[h][dn][rq * 4 + 1] + o[1]) * inv;
          float v2 = (Oc[h][dn][rq * 4 + 2] + o[2]) * inv;
          float v3 = (Oc[h][dn][rq * 4 + 3] + o[3]) * inv;
          int d0 = dn * 32 + rq * 8 + hi * 4;
          unsigned w0 = (unsigned)f2bf(v0) | ((unsigned)f2bf(v1) << 16);
          unsigned w1 = (unsigned)f2bf(v2) | ((unsigned)f2bf(v3) << 16);
          *(uint2*)(Oh + ob + d0) = make_uint2(w0, w1);
        }
    }
  }
}

extern "C" void kernel_launch(void* const* d_in, const int* in_sizes, int n_in,
                              void* d_out, int out_size, void* d_ws, size_t ws_size,
                              hipStream_t stream)
{
  const float* gene = (const float*)d_in[0];
  const float* expr = (const float*)d_in[1];
  const float* Mm   = (const float*)d_in[2];
  const float* Wf   = (const float*)d_in[3];
  const float* bfv  = (const float*)d_in[4];
  const float* Wq   = (const float*)d_in[5];
  const float* bq   = (const float*)d_in[6];
  const float* Wk   = (const float*)d_in[7];
  const float* bk   = (const float*)d_in[8];
  const float* Wv   = (const float*)d_in[9];
  const float* bv   = (const float*)d_in[10];
  const float* Wo   = (const float*)d_in[11];
  const float* bo   = (const float*)d_in[12];
  float* out = (float*)d_out;

  char* ws = (char*)d_ws;
  size_t off = 0;
  auto alloc = [&](size_t bytes) -> void* {
    void* p = (void*)(ws + off);
    off += (bytes + 255) & ~(size_t)255;
    return p;
  };
  u16* Xh   = (u16*)alloc(8192ull * 1024 * 2);
  u16* Xl   = (u16*)alloc(8192ull * 1024 * 2);
  u16* Wfth = (u16*)alloc(512ull * 1024 * 2);
  u16* Wftl = (u16*)alloc(512ull * 1024 * 2);
  u16* Wqth = (u16*)alloc(512ull * 512 * 2);
  u16* Wkth = (u16*)alloc(512ull * 512 * 2);
  u16* Wvth = (u16*)alloc(512ull * 512 * 2);
  u16* Woth = (u16*)alloc(512ull * 512 * 2);
  u16* Fh   = (u16*)alloc(8192ull * 512 * 2);
  u16* Fl   = (u16*)alloc(8192ull * 512 * 2);
  u16* Qh   = (u16*)alloc(8192ull * 512 * 2);
  u16* Kh   = (u16*)alloc(8192ull * 512 * 2);
  u16* Vt   = (u16*)alloc(8192ull * 512 * 2);
  // X is dead after the V projection; attention output aliases it.
  u16* Oh = Xh;

  const float QSC = 0.1803368801f;   // 0.125 * log2(e) — folded into Q, exp via exp2

  split_concat_kernel<<<8192, 256, 0, stream>>>(gene, expr, Xh, Xl);
  transpose_all_kernel<<<384, 256, 0, stream>>>(Wf, Wq, Wk, Wv, Wo,
                                                Wfth, Wftl, Wqth, Wkth, Wvth, Woth);

  // fused = X @ Wf + bf (full split, split output)
  gemm_kernel<3, 0, 0><<<dim3(64, 8), 256, 0, stream>>>(
      Xh, Xl, 1024, Wfth, Wftl, nullptr, 1024, bfv, nullptr, Fh, Fl, nullptr, 1.f, 1.f);
  // Q (pre-scaled) and K in one dual dispatch (A-split x W-hi)
  gemm_kernel<2, 1, 1><<<dim3(64, 16), 256, 0, stream>>>(
      Fh, Fl, 512, Wqth, nullptr, Wkth, 512, bq, bk, Qh, nullptr, Kh, QSC, 1.f);
  // V = expr @ Wv + bv -> bf16 V^T per head (A-split x W-hi)
  gemm_kernel<2, 2, 0><<<dim3(64, 8), 256, 0, stream>>>(
      Xh + 512, Xl + 512, 1024, Wvth, nullptr, nullptr, 512, bv, nullptr, Vt, nullptr, nullptr, 1.f, 1.f);
  // attention: 32x32 core, 2 heads/block, counted-vmcnt pipeline
  flash_kernel<<<dim3(32, 16), 256, 0, stream>>>(Qh, Kh, Vt, Mm, Oh);
  // out = O @ Wo + bo -> f32 (pure bf16)
  gemm_kernel<1, 3, 0><<<dim3(64, 8), 256, 0, stream>>>(
      Oh, nullptr, 512, Woth, nullptr, nullptr, 512, bo, nullptr, out, nullptr, nullptr, 1.f, 1.f);

  (void)in_sizes; (void)n_in; (void)out_size; (void)ws_size;
}

// Round 7
// 302.050 us; speedup vs baseline: 1.2182x; 1.2182x over previous
//
#include <hip/hip_runtime.h>

typedef unsigned short u16;
typedef __attribute__((ext_vector_type(8))) short bf16x8_t;
typedef __attribute__((ext_vector_type(4))) float f32x4_t;
typedef __attribute__((ext_vector_type(16))) float f32x16_t;

__device__ __forceinline__ u16 f2bf(float x){
  union { float f; unsigned u; } v; v.f = x;
  unsigned r = v.u + 0x7FFFu + ((v.u >> 16) & 1u);
  return (u16)(r >> 16);
}
__device__ __forceinline__ float bf2f(u16 h){
  union { unsigned u; float f; } v; v.u = ((unsigned)h) << 16;
  return v.f;
}
// truncation-pack two f32 -> (bf16(a) | bf16(b)<<16); bias cancels in renormalization
__device__ __forceinline__ unsigned pack_hi16(float a, float b){
  union { float f; unsigned u; } x, y; x.f = a; y.f = b;
  return (x.u >> 16) | (y.u & 0xFFFF0000u);
}

// async global->LDS DMA, 16B/lane; data lands at base + lane*16.
__device__ __forceinline__ void gl2lds16(const u16* g, u16* l){
  __builtin_amdgcn_global_load_lds((const __attribute__((address_space(1))) void*)g,
                                   (__attribute__((address_space(3))) void*)l, 16, 0, 0);
}

// ---- X = [gene|expr] concat, split into hi/lo bf16. 8192 rows x 1024 cols ----
__global__ __launch_bounds__(256) void split_concat_kernel(
    const float* __restrict__ gene, const float* __restrict__ expr,
    u16* __restrict__ Xh, u16* __restrict__ Xl)
{
  size_t e = ((size_t)blockIdx.x * 256 + threadIdx.x) * 4;
  int row = (int)(e >> 10);
  int col = (int)(e & 1023);
  const float* src = (col < 512) ? (gene + (size_t)row * 512 + col)
                                 : (expr + (size_t)row * 512 + (col - 512));
  float4 v = *(const float4*)src;
  float a[4] = {v.x, v.y, v.z, v.w};
  u16 hs[4], ls[4];
#pragma unroll
  for (int i = 0; i < 4; i++){
    hs[i] = f2bf(a[i]);
    ls[i] = f2bf(a[i] - bf2f(hs[i]));
  }
  *(uint2*)(Xh + e) = make_uint2(hs[0] | ((unsigned)hs[1] << 16), hs[2] | ((unsigned)hs[3] << 16));
  *(uint2*)(Xl + e) = make_uint2(ls[0] | ((unsigned)ls[1] << 16), ls[2] | ((unsigned)ls[3] << 16));
}

// ---- all weight transposes in ONE launch. W [K][N] f32 -> Wt [N][K] bf16 (hi, optional lo)
__global__ __launch_bounds__(256) void transpose_all_kernel(
    const float* __restrict__ Wf, const float* __restrict__ Wq,
    const float* __restrict__ Wk, const float* __restrict__ Wv,
    const float* __restrict__ Wo,
    u16* __restrict__ Wfth, u16* __restrict__ Wftl,
    u16* __restrict__ Wqth, u16* __restrict__ Wkth,
    u16* __restrict__ Wvth, u16* __restrict__ Woth)
{
  __shared__ float t[64][65];
  int id = blockIdx.x;
  const float* W; u16* Th; u16* Tl; int K, kx, ny;
  if (id < 128){ W = Wf; Th = Wfth; Tl = Wftl; K = 1024; kx = id >> 3; ny = id & 7; }
  else {
    int tt = id - 128; int wi = tt >> 6; tt &= 63; kx = tt >> 3; ny = tt & 7; K = 512;
    W  = (wi == 0) ? Wq  : (wi == 1) ? Wk  : (wi == 2) ? Wv  : Wo;
    Th = (wi == 0) ? Wqth: (wi == 1) ? Wkth: (wi == 2) ? Wvth: Woth;
    Tl = nullptr;
  }
  int k0 = kx * 64, n0 = ny * 64;
  int tid = threadIdx.x;
  int r = tid >> 4;
  int c4 = (tid & 15) * 4;
#pragma unroll
  for (int p = 0; p < 4; p++){
    int k = p * 16 + r;
    float4 v = *(const float4*)(W + (size_t)(k0 + k) * 512 + n0 + c4);
    t[c4 + 0][k] = v.x; t[c4 + 1][k] = v.y; t[c4 + 2][k] = v.z; t[c4 + 3][k] = v.w;
  }
  __syncthreads();
#pragma unroll
  for (int p = 0; p < 4; p++){
    int n = p * 16 + r;
    u16 hs[4], ls[4];
#pragma unroll
    for (int i = 0; i < 4; i++){
      float x = t[n][c4 + i];
      hs[i] = f2bf(x);
      ls[i] = f2bf(x - bf2f(hs[i]));
    }
    size_t o = (size_t)(n0 + n) * K + k0 + c4;
    *(uint2*)(Th + o) = make_uint2(hs[0] | ((unsigned)hs[1] << 16), hs[2] | ((unsigned)hs[3] << 16));
    if (Tl)
      *(uint2*)(Tl + o) = make_uint2(ls[0] | ((unsigned)ls[1] << 16), ls[2] | ((unsigned)ls[3] << 16));
  }
}

// ---- GEMM, templated on split count and output mode ----
// C[M][512] = A[M][K] @ B[K][512] + bias ; B given transposed [512][K].
// SPLITS: 3 = aH*bH + aH*bL + aL*bH ; 2 = aH*bH + aL*bH ; 1 = aH*bH
// MODE: 0 = split bf16 out (o0=hi,o1=lo) ; 1 = bf16 row-major, scaled
//       2 = bf16 V^T per head [(b*8+h)*64+d][s] ; 3 = f32 row-major
// DUAL: blockIdx.y>=8 selects second (Bh1,bias1,outsec,sc1) set.
// BM=128 BN=64 BK=32; 256 thr = 4 waves (2x2 of 64x32); XOR-swizzled LDS granules.
// XCD m-locality remap: linear bid -> XCD = lid%8 pins an m-GROUP (8 m-tiles =
// 1024 A-rows, 2-4MB hi+lo -> L2-resident per XCD); each XCD sweeps all n-panels
// from its own L2, so A enters each XCD once instead of once per n-panel (8x cut
// in L3->L2 A-traffic). Bijective: (l&7, (l>>3)&7, l>>6) -> (mgrp, msub, n).
// Requires gridDim.x == 64 and 512 blocks per side (all call sites comply).
template<int SPLITS, int MODE, int DUAL>
__global__ __launch_bounds__(256, 2) void gemm_kernel(
    const u16* __restrict__ Ah, const u16* __restrict__ Al, int lda,
    const u16* __restrict__ Bh0, const u16* __restrict__ Bl0,
    const u16* __restrict__ Bh1, int K,
    const float* __restrict__ bias0, const float* __restrict__ bias1,
    void* __restrict__ out0, void* __restrict__ out1, void* __restrict__ outsec,
    float sc0, float sc1)
{
  __shared__ __align__(16) u16 sAh[128 * 32];
  __shared__ __align__(16) u16 sAl[SPLITS >= 2 ? 128 * 32 : 8];
  __shared__ __align__(16) u16 sBh[64 * 32];
  __shared__ __align__(16) u16 sBl[SPLITS == 3 ? 64 * 32 : 8];
  int tid = threadIdx.x;
  int lane = tid & 63, w = tid >> 6, quad = lane >> 4, l15 = lane & 15;
  int wm = w & 1, wn = w >> 1;
  int lid = (int)(blockIdx.y * gridDim.x + blockIdx.x);
  int side = DUAL ? (lid >> 9) : 0;
  int l = lid & 511;
  int m0 = (((l & 7) << 3) | ((l >> 3) & 7)) * 128;
  int n0 = (l >> 6) * 64;
  const u16* Bh = (DUAL && side) ? Bh1 : Bh0;
  const float* bias = (DUAL && side) ? bias1 : bias0;
  void* o0 = (DUAL && side) ? outsec : out0;
  float sc = (DUAL && side) ? sc1 : sc0;

  f32x4_t acc[4][2];
#pragma unroll
  for (int i = 0; i < 4; i++)
#pragma unroll
    for (int j = 0; j < 2; j++)
#pragma unroll
      for (int r = 0; r < 4; r++) acc[i][j][r] = 0.f;

  int lrow = lane >> 2;
  int swzS = ((lane >> 2) & 3) ^ ((lane >> 4) & 3);
  int gkq  = ((lane & 3) ^ swzS) * 8;
  const u16* pAh0 = Ah + (size_t)(m0 + w * 32 + lrow) * lda + gkq;
  const u16* pAh1 = Ah + (size_t)(m0 + w * 32 + 16 + lrow) * lda + gkq;
  const u16* pAl0 = (SPLITS >= 2) ? Al + (size_t)(m0 + w * 32 + lrow) * lda + gkq : nullptr;
  const u16* pAl1 = (SPLITS >= 2) ? Al + (size_t)(m0 + w * 32 + 16 + lrow) * lda + gkq : nullptr;
  const u16* pBh0 = Bh + (size_t)(n0 + w * 16 + lrow) * K + gkq;
  const u16* pBl0 = (SPLITS == 3) ? Bl0 + (size_t)(n0 + w * 16 + lrow) * K + gkq : nullptr;
  u16* dAh = sAh + w * 1024;
  u16* dAl = sAl + w * 1024;
  u16* dBh = sBh + w * 512;
  u16* dBl = sBl + w * 512;

  int pq = (quad ^ ((l15 & 3) ^ ((l15 >> 2) & 3))) * 8;

  for (int k0 = 0; k0 < K; k0 += 32){
    __syncthreads();
    gl2lds16(pAh0 + k0, dAh);
    gl2lds16(pAh1 + k0, dAh + 512);
    if constexpr (SPLITS >= 2){
      gl2lds16(pAl0 + k0, dAl);
      gl2lds16(pAl1 + k0, dAl + 512);
    }
    gl2lds16(pBh0 + k0, dBh);
    if constexpr (SPLITS == 3)
      gl2lds16(pBl0 + k0, dBl);
    __syncthreads();

    bf16x8_t aH[4], aL[4], bH[2], bL[2];
#pragma unroll
    for (int mi = 0; mi < 4; mi++){
      int ad = (wm * 64 + mi * 16 + l15) * 32 + pq;
      aH[mi] = *(const bf16x8_t*)&sAh[ad];
      if constexpr (SPLITS >= 2) aL[mi] = *(const bf16x8_t*)&sAl[ad];
    }
#pragma unroll
    for (int ni = 0; ni < 2; ni++){
      int bd = (wn * 32 + ni * 16 + l15) * 32 + pq;
      bH[ni] = *(const bf16x8_t*)&sBh[bd];
      if constexpr (SPLITS == 3) bL[ni] = *(const bf16x8_t*)&sBl[bd];
    }
#pragma unroll
    for (int mi = 0; mi < 4; mi++)
#pragma unroll
      for (int ni = 0; ni < 2; ni++){
        acc[mi][ni] = __builtin_amdgcn_mfma_f32_16x16x32_bf16(aH[mi], bH[ni], acc[mi][ni], 0, 0, 0);
        if constexpr (SPLITS == 3)
          acc[mi][ni] = __builtin_amdgcn_mfma_f32_16x16x32_bf16(aH[mi], bL[ni], acc[mi][ni], 0, 0, 0);
        if constexpr (SPLITS >= 2)
          acc[mi][ni] = __builtin_amdgcn_mfma_f32_16x16x32_bf16(aL[mi], bH[ni], acc[mi][ni], 0, 0, 0);
      }
  }

#pragma unroll
  for (int mi = 0; mi < 4; mi++)
#pragma unroll
    for (int ni = 0; ni < 2; ni++){
      int gn = n0 + wn * 32 + ni * 16 + l15;
      float bs = bias[gn];
      int gm0 = m0 + wm * 64 + mi * 16 + quad * 4;
#pragma unroll
      for (int r = 0; r < 4; r++){
        float v = acc[mi][ni][r] + bs;
        int gm = gm0 + r;
        if constexpr (MODE == 0){
          u16 hb = f2bf(v);
          ((u16*)o0)[(size_t)gm * 512 + gn] = hb;
          ((u16*)out1)[(size_t)gm * 512 + gn] = f2bf(v - bf2f(hb));
        } else if constexpr (MODE == 1){
          ((u16*)o0)[(size_t)gm * 512 + gn] = f2bf(v * sc);
        } else if constexpr (MODE == 2){
          int bb = gm >> 11, s = gm & 2047;
          int hh = gn >> 6, d = gn & 63;
          ((u16*)o0)[((size_t)((bb * 8 + hh) * 64 + d) << 11) + s] = f2bf(v);
        } else {
          ((float*)o0)[(size_t)gm * 512 + gn] = v;
        }
      }
    }
}

// ---- flash attention v5 (reverted, verified 84.5us): 32x32x16 MFMA core,
// register-P via kv-permutation. Block = 4 waves (wq q-half, wk kv-half),
// 2 heads/block. S^T = mfma(K,Q): C col = lane&31 = q, C row r holds
// kv = wk*32 + phi(r); phi chosen so post-softmax P sits EXACTLY in the PV
// B-operand layout lane-locally: zero LDS round-trip, zero cross-lane ops.
// K LDS swizzle key = kv bits {4,3,0}; V key = d&7 (swizzle applied on the
// per-lane GLOBAL source column; LDS dest linear per global_load_lds).
// M: 4 float4/lane/iter following phi, prefetched one tile ahead.
// wk-halves reduce O and l once at the end through LDS.
// grid (32,16): x = q-tile, y = b*4 + head-pair; 512 blocks = 2/CU; bid%8 = x%8
// is head-pair-invariant -> M-sharing blocks land on one XCD.
__global__ __launch_bounds__(256, 2) void flash_kernel(
    const u16* __restrict__ Qh, const u16* __restrict__ Kh,
    const u16* __restrict__ Vt, const float* __restrict__ Mm,
    u16* __restrict__ Oh)
{
  __shared__ __align__(16) u16 sAll[2][16384];  // [buf][ K: 2h x 4096 | V: 2h x 4096 ]
  int tid = threadIdx.x, lane = tid & 63, w = tid >> 6;
  int ql = lane & 31, hi = lane >> 5;
  int wq = w >> 1, wk = w & 1;
  int by = blockIdx.y, b = by >> 2, h0 = (by & 3) * 2;
  int q0 = blockIdx.x * 64;
  int q  = q0 + wq * 32 + ql;

  // Q B-frags: lane holds Q[q][d = dt*16 + hi*8 + j]
  const u16* qp = Qh + ((size_t)(b * 2048 + q)) * 512 + h0 * 64 + hi * 8;
  bf16x8_t qf[2][4];
#pragma unroll
  for (int h = 0; h < 2; h++)
#pragma unroll
    for (int dt = 0; dt < 4; dt++)
      qf[h][dt] = *(const bf16x8_t*)(qp + h * 64 + dt * 16);

  // staging pointers: wave (wq=head, wk=row-half); 4 K-calls + 4 V-calls, 8 rows each
  int srow = lane >> 3, c8 = lane & 7;
  const u16* gK[4]; const u16* gV[4];
#pragma unroll
  for (int c = 0; c < 4; c++){
    int kv = wk * 32 + c * 8 + srow;                       // physical row in 64-tile
    int skey = ((c >> 1) << 2) | ((c & 1) << 1) | (srow & 1);   // kv bits {4,3,0}
    gK[c] = Kh + ((size_t)(b * 2048 + kv)) * 512 + (h0 + wq) * 64 + ((c8 ^ skey) << 3);
    gV[c] = Vt + ((size_t)((b * 8 + h0 + wq) * 64 + kv)) * 2048 + ((c8 ^ srow) << 3);
  }
  int dO = wq * 4096 + wk * 2048;   // u16 offset (within K or V section)

  // QK read: A row m=ql -> LDS row kvL = wk*32 + phi(ql)
  int phi = ((ql >> 3) & 1) * 16 + ((ql >> 2) & 1) * 8 + (ql >> 4) * 4 + (ql & 3);
  int kvL = wk * 32 + phi;
  int skr = ((ql >> 3) & 1) * 4 + ((ql >> 2) & 1) * 2 + (ql & 1);  // = key(kvL)
  int kaddr[4];
#pragma unroll
  for (int dt = 0; dt < 4; dt++)
    kaddr[dt] = kvL * 64 + (((dt * 2 + hi) ^ skr) << 3);
  // PV read: A row = d_local = ql; col chunk = wk*4 + kt*2 + hi, key = d&7
  int vaddr[2][2];
#pragma unroll
  for (int dn = 0; dn < 2; dn++)
#pragma unroll
    for (int kt = 0; kt < 2; kt++)
      vaddr[dn][kt] = (dn * 32 + ql) * 64 + (((wk * 4 + kt * 2 + hi) ^ (ql & 7)) << 3);

  // M: element reg of S -> kv = wk*32 + hi*8 + (g&1)*16 + (g>>1)*4 + e
  const float* mp = Mm + (size_t)b * (2048 * 2048) + (size_t)q * 2048 + wk * 32 + hi * 8;
  const int og[4] = {0, 16, 4, 20};

  float lp[2] = {0.f, 0.f};
  f32x16_t Oc[2][2];
#pragma unroll
  for (int h = 0; h < 2; h++)
#pragma unroll
    for (int dn = 0; dn < 2; dn++)
#pragma unroll
      for (int r = 0; r < 16; r++) Oc[h][dn][r] = 0.f;

#define STAGE(B, KK) do {                                              \
    _Pragma("unroll")                                                  \
    for (int c = 0; c < 4; c++){                                       \
      gl2lds16(gK[c] + (size_t)(KK) * 512, &sAll[B][dO + c * 512]);    \
      gl2lds16(gV[c] + (KK),               &sAll[B][8192 + dO + c * 512]); \
    }                                                                  \
  } while (0)

  // prologue
  STAGE(0, 0);
  f32x4_t Mc[4], Mn[4];
#pragma unroll
  for (int g = 0; g < 4; g++) Mc[g] = *(const f32x4_t*)(mp + og[g]);
  __syncthreads();

  for (int t = 0; t < 32; ++t){
    int ph = t & 1;
    bool nx = t < 31;
    if (nx) STAGE(ph ^ 1, (t + 1) * 64);
    if (nx){
#pragma unroll
      for (int g = 0; g < 4; g++) Mn[g] = *(const f32x4_t*)(mp + (t + 1) * 64 + og[g]);
    }
    const u16* kb = &sAll[ph][0];
    const u16* vb = &sAll[ph][8192];

#pragma unroll
    for (int h = 0; h < 2; ++h){
      const u16* kbh = kb + h * 4096;
      const u16* vbh = vb + h * 4096;

      f32x16_t S;
#pragma unroll
      for (int r = 0; r < 16; r++) S[r] = 0.f;
#pragma unroll
      for (int dt = 0; dt < 4; dt++){
        bf16x8_t kf = *(const bf16x8_t*)&kbh[kaddr[dt]];
        S = __builtin_amdgcn_mfma_f32_32x32x16_bf16(kf, qf[h][dt], S, 0, 0, 0);
      }

      // p = M * exp2(s*M); lp accumulates; P packed into PV B-frags lane-locally
      float p[16];
#pragma unroll
      for (int g = 0; g < 4; g++)
#pragma unroll
        for (int e = 0; e < 4; e++){
          float m = Mc[g][e];
          float v = m * __builtin_amdgcn_exp2f(S[g * 4 + e] * m);
          lp[h] += v;
          p[g * 4 + e] = v;
        }
#pragma unroll
      for (int kt = 0; kt < 2; kt++){
        union { unsigned u[4]; bf16x8_t v8; } pb;
        pb.u[0] = pack_hi16(p[kt * 4 + 0], p[kt * 4 + 1]);
        pb.u[1] = pack_hi16(p[kt * 4 + 2], p[kt * 4 + 3]);
        pb.u[2] = pack_hi16(p[kt * 4 + 8], p[kt * 4 + 9]);
        pb.u[3] = pack_hi16(p[kt * 4 + 10], p[kt * 4 + 11]);
#pragma unroll
        for (int dn = 0; dn < 2; dn++){
          bf16x8_t vf = *(const bf16x8_t*)&vbh[vaddr[dn][kt]];
          Oc[h][dn] = __builtin_amdgcn_mfma_f32_32x32x16_bf16(vf, pb.v8, Oc[h][dn], 0, 0, 0);
        }
      }
    }

    __syncthreads();   // drains next-tile DMAs (issued pre-compute) + releases bufs
    if (nx){
#pragma unroll
      for (int g = 0; g < 4; g++) Mc[g] = Mn[g];
    }
  }
#undef STAGE

  // hi-halves hold disjoint kv -> sum across lane^32
  lp[0] += __shfl_xor(lp[0], 32);
  lp[1] += __shfl_xor(lp[1], 32);

  // reduce O and l across the two wk-halves via LDS (buffers are dead now)
  float* red = (float*)&sAll[0][0];
  float* lpr = red + 8192;
  if (wk){
#pragma unroll
    for (int h = 0; h < 2; h++){
#pragma unroll
      for (int dn = 0; dn < 2; dn++)
#pragma unroll
        for (int rq = 0; rq < 4; rq++){
          f32x4_t o;
          o[0] = Oc[h][dn][rq * 4 + 0]; o[1] = Oc[h][dn][rq * 4 + 1];
          o[2] = Oc[h][dn][rq * 4 + 2]; o[3] = Oc[h][dn][rq * 4 + 3];
          *(f32x4_t*)&red[((((wq * 2 + h) * 2 + dn) * 4 + rq) * 64 + lane) * 4] = o;
        }
      lpr[(wq * 2 + h) * 64 + lane] = lp[h];
    }
  }
  __syncthreads();
  if (!wk){
#pragma unroll
    for (int h = 0; h < 2; h++){
      float li = lp[h] + lpr[(wq * 2 + h) * 64 + lane];
      float inv = 1.0f / li;
      size_t ob = ((size_t)(b * 2048 + q)) * 512 + (h0 + h) * 64;
#pragma unroll
      for (int dn = 0; dn < 2; dn++)
#pragma unroll
        for (int rq = 0; rq < 4; rq++){
          f32x4_t o = *(const f32x4_t*)&red[((((wq * 2 + h) * 2 + dn) * 4 + rq) * 64 + lane) * 4];
          float v0 = (Oc[h][dn][rq * 4 + 0] + o[0]) * inv;
          float v1 = (Oc[h][dn][rq * 4 + 1] + o[1]) * inv;
          float v2 = (Oc[h][dn][rq * 4 + 2] + o[2]) * inv;
          float v3 = (Oc[h][dn][rq * 4 + 3] + o[3]) * inv;
          int d0 = dn * 32 + rq * 8 + hi * 4;
          unsigned w0 = (unsigned)f2bf(v0) | ((unsigned)f2bf(v1) << 16);
          unsigned w1 = (unsigned)f2bf(v2) | ((unsigned)f2bf(v3) << 16);
          *(uint2*)(Oh + ob + d0) = make_uint2(w0, w1);
        }
    }
  }
}

extern "C" void kernel_launch(void* const* d_in, const int* in_sizes, int n_in,
                              void* d_out, int out_size, void* d_ws, size_t ws_size,
                              hipStream_t stream)
{
  const float* gene = (const float*)d_in[0];
  const float* expr = (const float*)d_in[1];
  const float* Mm   = (const float*)d_in[2];
  const float* Wf   = (const float*)d_in[3];
  const float* bfv  = (const float*)d_in[4];
  const float* Wq   = (const float*)d_in[5];
  const float* bq   = (const float*)d_in[6];
  const float* Wk   = (const float*)d_in[7];
  const float* bk   = (const float*)d_in[8];
  const float* Wv   = (const float*)d_in[9];
  const float* bv   = (const float*)d_in[10];
  const float* Wo   = (const float*)d_in[11];
  const float* bo   = (const float*)d_in[12];
  float* out = (float*)d_out;

  char* ws = (char*)d_ws;
  size_t off = 0;
  auto alloc = [&](size_t bytes) -> void* {
    void* p = (void*)(ws + off);
    off += (bytes + 255) & ~(size_t)255;
    return p;
  };
  u16* Xh   = (u16*)alloc(8192ull * 1024 * 2);
  u16* Xl   = (u16*)alloc(8192ull * 1024 * 2);
  u16* Wfth = (u16*)alloc(512ull * 1024 * 2);
  u16* Wftl = (u16*)alloc(512ull * 1024 * 2);
  u16* Wqth = (u16*)alloc(512ull * 512 * 2);
  u16* Wkth = (u16*)alloc(512ull * 512 * 2);
  u16* Wvth = (u16*)alloc(512ull * 512 * 2);
  u16* Woth = (u16*)alloc(512ull * 512 * 2);
  u16* Fh   = (u16*)alloc(8192ull * 512 * 2);
  u16* Fl   = (u16*)alloc(8192ull * 512 * 2);
  u16* Qh   = (u16*)alloc(8192ull * 512 * 2);
  u16* Kh   = (u16*)alloc(8192ull * 512 * 2);
  u16* Vt   = (u16*)alloc(8192ull * 512 * 2);
  // X is dead after the V projection; attention output aliases it.
  u16* Oh = Xh;

  const float QSC = 0.1803368801f;   // 0.125 * log2(e) — folded into Q, exp via exp2

  split_concat_kernel<<<8192, 256, 0, stream>>>(gene, expr, Xh, Xl);
  transpose_all_kernel<<<384, 256, 0, stream>>>(Wf, Wq, Wk, Wv, Wo,
                                                Wfth, Wftl, Wqth, Wkth, Wvth, Woth);

  // fused = X @ Wf + bf (full split, split output)
  gemm_kernel<3, 0, 0><<<dim3(64, 8), 256, 0, stream>>>(
      Xh, Xl, 1024, Wfth, Wftl, nullptr, 1024, bfv, nullptr, Fh, Fl, nullptr, 1.f, 1.f);
  // Q (pre-scaled) and K in one dual dispatch (A-split x W-hi)
  gemm_kernel<2, 1, 1><<<dim3(64, 16), 256, 0, stream>>>(
      Fh, Fl, 512, Wqth, nullptr, Wkth, 512, bq, bk, Qh, nullptr, Kh, QSC, 1.f);
  // V = expr @ Wv + bv -> bf16 V^T per head (A-split x W-hi)
  gemm_kernel<2, 2, 0><<<dim3(64, 8), 256, 0, stream>>>(
      Xh + 512, Xl + 512, 1024, Wvth, nullptr, nullptr, 512, bv, nullptr, Vt, nullptr, nullptr, 1.f, 1.f);
  // attention: 32x32 core, 2 heads/block, kv-split waves
  flash_kernel<<<dim3(32, 16), 256, 0, stream>>>(Qh, Kh, Vt, Mm, Oh);
  // out = O @ Wo + bo -> f32 (pure bf16)
  gemm_kernel<1, 3, 0><<<dim3(64, 8), 256, 0, stream>>>(
      Oh, nullptr, 512, Woth, nullptr, nullptr, 512, bo, nullptr, out, nullptr, nullptr, 1.f, 1.f);

  (void)in_sizes; (void)n_in; (void)out_size; (void)ws_size;
}

// Round 8
// 301.379 us; speedup vs baseline: 1.2209x; 1.0022x over previous
//
#include <hip/hip_runtime.h>

typedef unsigned short u16;
typedef __attribute__((ext_vector_type(8))) short bf16x8_t;
typedef __attribute__((ext_vector_type(4))) float f32x4_t;
typedef __attribute__((ext_vector_type(16))) float f32x16_t;

__device__ __forceinline__ u16 f2bf(float x){
  union { float f; unsigned u; } v; v.f = x;
  unsigned r = v.u + 0x7FFFu + ((v.u >> 16) & 1u);
  return (u16)(r >> 16);
}
__device__ __forceinline__ float bf2f(u16 h){
  union { unsigned u; float f; } v; v.u = ((unsigned)h) << 16;
  return v.f;
}
// truncation-pack two f32 -> (bf16(a) | bf16(b)<<16); bias cancels in renormalization
__device__ __forceinline__ unsigned pack_hi16(float a, float b){
  union { float f; unsigned u; } x, y; x.f = a; y.f = b;
  return (x.u >> 16) | (y.u & 0xFFFF0000u);
}

// async global->LDS DMA, 16B/lane; data lands at base + lane*16.
__device__ __forceinline__ void gl2lds16(const u16* g, u16* l){
  __builtin_amdgcn_global_load_lds((const __attribute__((address_space(1))) void*)g,
                                   (__attribute__((address_space(3))) void*)l, 16, 0, 0);
}

// ---- X = [gene|expr] concat, split into hi/lo bf16. 8192 rows x 1024 cols ----
__global__ __launch_bounds__(256) void split_concat_kernel(
    const float* __restrict__ gene, const float* __restrict__ expr,
    u16* __restrict__ Xh, u16* __restrict__ Xl)
{
  size_t e = ((size_t)blockIdx.x * 256 + threadIdx.x) * 4;
  int row = (int)(e >> 10);
  int col = (int)(e & 1023);
  const float* src = (col < 512) ? (gene + (size_t)row * 512 + col)
                                 : (expr + (size_t)row * 512 + (col - 512));
  float4 v = *(const float4*)src;
  float a[4] = {v.x, v.y, v.z, v.w};
  u16 hs[4], ls[4];
#pragma unroll
  for (int i = 0; i < 4; i++){
    hs[i] = f2bf(a[i]);
    ls[i] = f2bf(a[i] - bf2f(hs[i]));
  }
  *(uint2*)(Xh + e) = make_uint2(hs[0] | ((unsigned)hs[1] << 16), hs[2] | ((unsigned)hs[3] << 16));
  *(uint2*)(Xl + e) = make_uint2(ls[0] | ((unsigned)ls[1] << 16), ls[2] | ((unsigned)ls[3] << 16));
}

// ---- all weight transposes in ONE launch. W [K][N] f32 -> Wt [N][K] bf16 (hi, optional lo)
__global__ __launch_bounds__(256) void transpose_all_kernel(
    const float* __restrict__ Wf, const float* __restrict__ Wq,
    const float* __restrict__ Wk, const float* __restrict__ Wv,
    const float* __restrict__ Wo,
    u16* __restrict__ Wfth, u16* __restrict__ Wftl,
    u16* __restrict__ Wqth, u16* __restrict__ Wkth,
    u16* __restrict__ Wvth, u16* __restrict__ Woth)
{
  __shared__ float t[64][65];
  int id = blockIdx.x;
  const float* W; u16* Th; u16* Tl; int K, kx, ny;
  if (id < 128){ W = Wf; Th = Wfth; Tl = Wftl; K = 1024; kx = id >> 3; ny = id & 7; }
  else {
    int tt = id - 128; int wi = tt >> 6; tt &= 63; kx = tt >> 3; ny = tt & 7; K = 512;
    W  = (wi == 0) ? Wq  : (wi == 1) ? Wk  : (wi == 2) ? Wv  : Wo;
    Th = (wi == 0) ? Wqth: (wi == 1) ? Wkth: (wi == 2) ? Wvth: Woth;
    Tl = nullptr;
  }
  int k0 = kx * 64, n0 = ny * 64;
  int tid = threadIdx.x;
  int r = tid >> 4;
  int c4 = (tid & 15) * 4;
#pragma unroll
  for (int p = 0; p < 4; p++){
    int k = p * 16 + r;
    float4 v = *(const float4*)(W + (size_t)(k0 + k) * 512 + n0 + c4);
    t[c4 + 0][k] = v.x; t[c4 + 1][k] = v.y; t[c4 + 2][k] = v.z; t[c4 + 3][k] = v.w;
  }
  __syncthreads();
#pragma unroll
  for (int p = 0; p < 4; p++){
    int n = p * 16 + r;
    u16 hs[4], ls[4];
#pragma unroll
    for (int i = 0; i < 4; i++){
      float x = t[n][c4 + i];
      hs[i] = f2bf(x);
      ls[i] = f2bf(x - bf2f(hs[i]));
    }
    size_t o = (size_t)(n0 + n) * K + k0 + c4;
    *(uint2*)(Th + o) = make_uint2(hs[0] | ((unsigned)hs[1] << 16), hs[2] | ((unsigned)hs[3] << 16));
    if (Tl)
      *(uint2*)(Tl + o) = make_uint2(ls[0] | ((unsigned)ls[1] << 16), ls[2] | ((unsigned)ls[3] << 16));
  }
}

// ---- GEMM, templated on split count and output mode ----
// C[M][512] = A[M][K] @ B[K][512] + bias ; B given transposed [512][K].
// SPLITS: 3 = aH*bH + aH*bL + aL*bH ; 2 = aH*bH + aL*bH ; 1 = aH*bH
// MODE: 0 = split bf16 out (o0=hi,o1=lo) ; 1 = bf16 row-major, scaled
//       2 = bf16 V^T per head [(b*8+h)*64+d][s] ; 3 = f32 row-major
// DUAL: lid>=512 selects second (Bh1,bias1,outsec,sc1) set.
// BM=128 BN=64 BK=32; 256 thr = 4 waves (2x2 of 64x32); XOR-swizzled LDS granules.
// v7: DOUBLE-BUFFERED single-barrier K-loop (flash-v4 discipline): stage(next buf)
// is issued BEFORE compute(cur buf); the compiler's vmcnt(0)-before-barrier then
// drains next-tile DMAs AFTER the current tile's MFMAs instead of before them, and
// one barrier per K-step disappears. Old structure exposed full DMA latency
// (~300-600cy) serially every K-step vs ~120-240cy of compute (=> ~11% MfmaUtil).
// XCD m-locality remap kept (neutral, harmless).
template<int SPLITS, int MODE, int DUAL>
__global__ __launch_bounds__(256, 2) void gemm_kernel(
    const u16* __restrict__ Ah, const u16* __restrict__ Al, int lda,
    const u16* __restrict__ Bh0, const u16* __restrict__ Bl0,
    const u16* __restrict__ Bh1, int K,
    const float* __restrict__ bias0, const float* __restrict__ bias1,
    void* __restrict__ out0, void* __restrict__ out1, void* __restrict__ outsec,
    float sc0, float sc1)
{
  __shared__ __align__(16) u16 sAh[2][128 * 32];
  __shared__ __align__(16) u16 sAl[SPLITS >= 2 ? 2 : 1][SPLITS >= 2 ? 128 * 32 : 8];
  __shared__ __align__(16) u16 sBh[2][64 * 32];
  __shared__ __align__(16) u16 sBl[SPLITS == 3 ? 2 : 1][SPLITS == 3 ? 64 * 32 : 8];
  int tid = threadIdx.x;
  int lane = tid & 63, w = tid >> 6, quad = lane >> 4, l15 = lane & 15;
  int wm = w & 1, wn = w >> 1;
  int lid = (int)(blockIdx.y * gridDim.x + blockIdx.x);
  int side = DUAL ? (lid >> 9) : 0;
  int l = lid & 511;
  int m0 = (((l & 7) << 3) | ((l >> 3) & 7)) * 128;
  int n0 = (l >> 6) * 64;
  const u16* Bh = (DUAL && side) ? Bh1 : Bh0;
  const float* bias = (DUAL && side) ? bias1 : bias0;
  void* o0 = (DUAL && side) ? outsec : out0;
  float sc = (DUAL && side) ? sc1 : sc0;

  f32x4_t acc[4][2];
#pragma unroll
  for (int i = 0; i < 4; i++)
#pragma unroll
    for (int j = 0; j < 2; j++)
#pragma unroll
      for (int r = 0; r < 4; r++) acc[i][j][r] = 0.f;

  int lrow = lane >> 2;
  int swzS = ((lane >> 2) & 3) ^ ((lane >> 4) & 3);
  int gkq  = ((lane & 3) ^ swzS) * 8;
  const u16* pAh0 = Ah + (size_t)(m0 + w * 32 + lrow) * lda + gkq;
  const u16* pAh1 = Ah + (size_t)(m0 + w * 32 + 16 + lrow) * lda + gkq;
  const u16* pAl0 = (SPLITS >= 2) ? Al + (size_t)(m0 + w * 32 + lrow) * lda + gkq : nullptr;
  const u16* pAl1 = (SPLITS >= 2) ? Al + (size_t)(m0 + w * 32 + 16 + lrow) * lda + gkq : nullptr;
  const u16* pBh0 = Bh + (size_t)(n0 + w * 16 + lrow) * K + gkq;
  const u16* pBl0 = (SPLITS == 3) ? Bl0 + (size_t)(n0 + w * 16 + lrow) * K + gkq : nullptr;

  int pq = (quad ^ ((l15 & 3) ^ ((l15 >> 2) & 3))) * 8;

#define STAGEG(B, KK) do {                                                 \
    gl2lds16(pAh0 + (KK), &sAh[B][w * 1024]);                              \
    gl2lds16(pAh1 + (KK), &sAh[B][w * 1024 + 512]);                        \
    if constexpr (SPLITS >= 2){                                            \
      gl2lds16(pAl0 + (KK), &sAl[B][w * 1024]);                            \
      gl2lds16(pAl1 + (KK), &sAl[B][w * 1024 + 512]);                      \
    }                                                                      \
    gl2lds16(pBh0 + (KK), &sBh[B][w * 512]);                               \
    if constexpr (SPLITS == 3)                                             \
      gl2lds16(pBl0 + (KK), &sBl[B][w * 512]);                             \
  } while (0)

  // prologue: stage tile 0 into buf 0; barrier drains it.
  STAGEG(0, 0);
  __syncthreads();

  int T = K >> 5;
  for (int t = 0; t < T; ++t){
    int ph = t & 1;
    bool nx = (t + 1) < T;
    if (nx) STAGEG(ph ^ 1, (t + 1) * 32);

    bf16x8_t aH[4], aL[4], bH[2], bL[2];
#pragma unroll
    for (int mi = 0; mi < 4; mi++){
      int ad = (wm * 64 + mi * 16 + l15) * 32 + pq;
      aH[mi] = *(const bf16x8_t*)&sAh[ph][ad];
      if constexpr (SPLITS >= 2) aL[mi] = *(const bf16x8_t*)&sAl[ph][ad];
    }
#pragma unroll
    for (int ni = 0; ni < 2; ni++){
      int bd = (wn * 32 + ni * 16 + l15) * 32 + pq;
      bH[ni] = *(const bf16x8_t*)&sBh[ph][bd];
      if constexpr (SPLITS == 3) bL[ni] = *(const bf16x8_t*)&sBl[ph][bd];
    }
#pragma unroll
    for (int mi = 0; mi < 4; mi++)
#pragma unroll
      for (int ni = 0; ni < 2; ni++){
        acc[mi][ni] = __builtin_amdgcn_mfma_f32_16x16x32_bf16(aH[mi], bH[ni], acc[mi][ni], 0, 0, 0);
        if constexpr (SPLITS == 3)
          acc[mi][ni] = __builtin_amdgcn_mfma_f32_16x16x32_bf16(aH[mi], bL[ni], acc[mi][ni], 0, 0, 0);
        if constexpr (SPLITS >= 2)
          acc[mi][ni] = __builtin_amdgcn_mfma_f32_16x16x32_bf16(aL[mi], bH[ni], acc[mi][ni], 0, 0, 0);
      }

    if (nx) __syncthreads();   // drains next-tile DMAs (post-compute) + releases buf
  }
#undef STAGEG

#pragma unroll
  for (int mi = 0; mi < 4; mi++)
#pragma unroll
    for (int ni = 0; ni < 2; ni++){
      int gn = n0 + wn * 32 + ni * 16 + l15;
      float bs = bias[gn];
      int gm0 = m0 + wm * 64 + mi * 16 + quad * 4;
#pragma unroll
      for (int r = 0; r < 4; r++){
        float v = acc[mi][ni][r] + bs;
        int gm = gm0 + r;
        if constexpr (MODE == 0){
          u16 hb = f2bf(v);
          ((u16*)o0)[(size_t)gm * 512 + gn] = hb;
          ((u16*)out1)[(size_t)gm * 512 + gn] = f2bf(v - bf2f(hb));
        } else if constexpr (MODE == 1){
          ((u16*)o0)[(size_t)gm * 512 + gn] = f2bf(v * sc);
        } else if constexpr (MODE == 2){
          int bb = gm >> 11, s = gm & 2047;
          int hh = gn >> 6, d = gn & 63;
          ((u16*)o0)[((size_t)((bb * 8 + hh) * 64 + d) << 11) + s] = f2bf(v);
        } else {
          ((float*)o0)[(size_t)gm * 512 + gn] = v;
        }
      }
    }
}

// ---- flash attention v5 (verified 84.5us, byte-identical): 32x32x16 MFMA core,
// register-P via kv-permutation. Block = 4 waves (wq q-half, wk kv-half),
// 2 heads/block. S^T = mfma(K,Q): C col = lane&31 = q, C row r holds
// kv = wk*32 + phi(r); phi chosen so post-softmax P sits EXACTLY in the PV
// B-operand layout lane-locally: zero LDS round-trip, zero cross-lane ops.
// K LDS swizzle key = kv bits {4,3,0}; V key = d&7 (swizzle applied on the
// per-lane GLOBAL source column; LDS dest linear per global_load_lds).
// M: 4 float4/lane/iter following phi, prefetched one tile ahead.
// wk-halves reduce O and l once at the end through LDS.
// grid (32,16): x = q-tile, y = b*4 + head-pair; 512 blocks = 2/CU.
__global__ __launch_bounds__(256, 2) void flash_kernel(
    const u16* __restrict__ Qh, const u16* __restrict__ Kh,
    const u16* __restrict__ Vt, const float* __restrict__ Mm,
    u16* __restrict__ Oh)
{
  __shared__ __align__(16) u16 sAll[2][16384];  // [buf][ K: 2h x 4096 | V: 2h x 4096 ]
  int tid = threadIdx.x, lane = tid & 63, w = tid >> 6;
  int ql = lane & 31, hi = lane >> 5;
  int wq = w >> 1, wk = w & 1;
  int by = blockIdx.y, b = by >> 2, h0 = (by & 3) * 2;
  int q0 = blockIdx.x * 64;
  int q  = q0 + wq * 32 + ql;

  // Q B-frags: lane holds Q[q][d = dt*16 + hi*8 + j]
  const u16* qp = Qh + ((size_t)(b * 2048 + q)) * 512 + h0 * 64 + hi * 8;
  bf16x8_t qf[2][4];
#pragma unroll
  for (int h = 0; h < 2; h++)
#pragma unroll
    for (int dt = 0; dt < 4; dt++)
      qf[h][dt] = *(const bf16x8_t*)(qp + h * 64 + dt * 16);

  // staging pointers: wave (wq=head, wk=row-half); 4 K-calls + 4 V-calls, 8 rows each
  int srow = lane >> 3, c8 = lane & 7;
  const u16* gK[4]; const u16* gV[4];
#pragma unroll
  for (int c = 0; c < 4; c++){
    int kv = wk * 32 + c * 8 + srow;                       // physical row in 64-tile
    int skey = ((c >> 1) << 2) | ((c & 1) << 1) | (srow & 1);   // kv bits {4,3,0}
    gK[c] = Kh + ((size_t)(b * 2048 + kv)) * 512 + (h0 + wq) * 64 + ((c8 ^ skey) << 3);
    gV[c] = Vt + ((size_t)((b * 8 + h0 + wq) * 64 + kv)) * 2048 + ((c8 ^ srow) << 3);
  }
  int dO = wq * 4096 + wk * 2048;   // u16 offset (within K or V section)

  // QK read: A row m=ql -> LDS row kvL = wk*32 + phi(ql)
  int phi = ((ql >> 3) & 1) * 16 + ((ql >> 2) & 1) * 8 + (ql >> 4) * 4 + (ql & 3);
  int kvL = wk * 32 + phi;
  int skr = ((ql >> 3) & 1) * 4 + ((ql >> 2) & 1) * 2 + (ql & 1);  // = key(kvL)
  int kaddr[4];
#pragma unroll
  for (int dt = 0; dt < 4; dt++)
    kaddr[dt] = kvL * 64 + (((dt * 2 + hi) ^ skr) << 3);
  // PV read: A row = d_local = ql; col chunk = wk*4 + kt*2 + hi, key = d&7
  int vaddr[2][2];
#pragma unroll
  for (int dn = 0; dn < 2; dn++)
#pragma unroll
    for (int kt = 0; kt < 2; kt++)
      vaddr[dn][kt] = (dn * 32 + ql) * 64 + (((wk * 4 + kt * 2 + hi) ^ (ql & 7)) << 3);

  // M: element reg of S -> kv = wk*32 + hi*8 + (g&1)*16 + (g>>1)*4 + e
  const float* mp = Mm + (size_t)b * (2048 * 2048) + (size_t)q * 2048 + wk * 32 + hi * 8;
  const int og[4] = {0, 16, 4, 20};

  float lp[2] = {0.f, 0.f};
  f32x16_t Oc[2][2];
#pragma unroll
  for (int h = 0; h < 2; h++)
#pragma unroll
    for (int dn = 0; dn < 2; dn++)
#pragma unroll
      for (int r = 0; r < 16; r++) Oc[h][dn][r] = 0.f;

#define STAGE(B, KK) do {                                              \
    _Pragma("unroll")                                                  \
    for (int c = 0; c < 4; c++){                                       \
      gl2lds16(gK[c] + (size_t)(KK) * 512, &sAll[B][dO + c * 512]);    \
      gl2lds16(gV[c] + (KK),               &sAll[B][8192 + dO + c * 512]); \
    }                                                                  \
  } while (0)

  // prologue
  STAGE(0, 0);
  f32x4_t Mc[4], Mn[4];
#pragma unroll
  for (int g = 0; g < 4; g++) Mc[g] = *(const f32x4_t*)(mp + og[g]);
  __syncthreads();

  for (int t = 0; t < 32; ++t){
    int ph = t & 1;
    bool nx = t < 31;
    if (nx) STAGE(ph ^ 1, (t + 1) * 64);
    if (nx){
#pragma unroll
      for (int g = 0; g < 4; g++) Mn[g] = *(const f32x4_t*)(mp + (t + 1) * 64 + og[g]);
    }
    const u16* kb = &sAll[ph][0];
    const u16* vb = &sAll[ph][8192];

#pragma unroll
    for (int h = 0; h < 2; ++h){
      const u16* kbh = kb + h * 4096;
      const u16* vbh = vb + h * 4096;

      f32x16_t S;
#pragma unroll
      for (int r = 0; r < 16; r++) S[r] = 0.f;
#pragma unroll
      for (int dt = 0; dt < 4; dt++){
        bf16x8_t kf = *(const bf16x8_t*)&kbh[kaddr[dt]];
        S = __builtin_amdgcn_mfma_f32_32x32x16_bf16(kf, qf[h][dt], S, 0, 0, 0);
      }

      // p = M * exp2(s*M); lp accumulates; P packed into PV B-frags lane-locally
      float p[16];
#pragma unroll
      for (int g = 0; g < 4; g++)
#pragma unroll
        for (int e = 0; e < 4; e++){
          float m = Mc[g][e];
          float v = m * __builtin_amdgcn_exp2f(S[g * 4 + e] * m);
          lp[h] += v;
          p[g * 4 + e] = v;
        }
#pragma unroll
      for (int kt = 0; kt < 2; kt++){
        union { unsigned u[4]; bf16x8_t v8; } pb;
        pb.u[0] = pack_hi16(p[kt * 4 + 0], p[kt * 4 + 1]);
        pb.u[1] = pack_hi16(p[kt * 4 + 2], p[kt * 4 + 3]);
        pb.u[2] = pack_hi16(p[kt * 4 + 8], p[kt * 4 + 9]);
        pb.u[3] = pack_hi16(p[kt * 4 + 10], p[kt * 4 + 11]);
#pragma unroll
        for (int dn = 0; dn < 2; dn++){
          bf16x8_t vf = *(const bf16x8_t*)&vbh[vaddr[dn][kt]];
          Oc[h][dn] = __builtin_amdgcn_mfma_f32_32x32x16_bf16(vf, pb.v8, Oc[h][dn], 0, 0, 0);
        }
      }
    }

    __syncthreads();   // drains next-tile DMAs (issued pre-compute) + releases bufs
    if (nx){
#pragma unroll
      for (int g = 0; g < 4; g++) Mc[g] = Mn[g];
    }
  }
#undef STAGE

  // hi-halves hold disjoint kv -> sum across lane^32
  lp[0] += __shfl_xor(lp[0], 32);
  lp[1] += __shfl_xor(lp[1], 32);

  // reduce O and l across the two wk-halves via LDS (buffers are dead now)
  float* red = (float*)&sAll[0][0];
  float* lpr = red + 8192;
  if (wk){
#pragma unroll
    for (int h = 0; h < 2; h++){
#pragma unroll
      for (int dn = 0; dn < 2; dn++)
#pragma unroll
        for (int rq = 0; rq < 4; rq++){
          f32x4_t o;
          o[0] = Oc[h][dn][rq * 4 + 0]; o[1] = Oc[h][dn][rq * 4 + 1];
          o[2] = Oc[h][dn][rq * 4 + 2]; o[3] = Oc[h][dn][rq * 4 + 3];
          *(f32x4_t*)&red[((((wq * 2 + h) * 2 + dn) * 4 + rq) * 64 + lane) * 4] = o;
        }
      lpr[(wq * 2 + h) * 64 + lane] = lp[h];
    }
  }
  __syncthreads();
  if (!wk){
#pragma unroll
    for (int h = 0; h < 2; h++){
      float li = lp[h] + lpr[(wq * 2 + h) * 64 + lane];
      float inv = 1.0f / li;
      size_t ob = ((size_t)(b * 2048 + q)) * 512 + (h0 + h) * 64;
#pragma unroll
      for (int dn = 0; dn < 2; dn++)
#pragma unroll
        for (int rq = 0; rq < 4; rq++){
          f32x4_t o = *(const f32x4_t*)&red[((((wq * 2 + h) * 2 + dn) * 4 + rq) * 64 + lane) * 4];
          float v0 = (Oc[h][dn][rq * 4 + 0] + o[0]) * inv;
          float v1 = (Oc[h][dn][rq * 4 + 1] + o[1]) * inv;
          float v2 = (Oc[h][dn][rq * 4 + 2] + o[2]) * inv;
          float v3 = (Oc[h][dn][rq * 4 + 3] + o[3]) * inv;
          int d0 = dn * 32 + rq * 8 + hi * 4;
          unsigned w0 = (unsigned)f2bf(v0) | ((unsigned)f2bf(v1) << 16);
          unsigned w1 = (unsigned)f2bf(v2) | ((unsigned)f2bf(v3) << 16);
          *(uint2*)(Oh + ob + d0) = make_uint2(w0, w1);
        }
    }
  }
}

extern "C" void kernel_launch(void* const* d_in, const int* in_sizes, int n_in,
                              void* d_out, int out_size, void* d_ws, size_t ws_size,
                              hipStream_t stream)
{
  const float* gene = (const float*)d_in[0];
  const float* expr = (const float*)d_in[1];
  const float* Mm   = (const float*)d_in[2];
  const float* Wf   = (const float*)d_in[3];
  const float* bfv  = (const float*)d_in[4];
  const float* Wq   = (const float*)d_in[5];
  const float* bq   = (const float*)d_in[6];
  const float* Wk   = (const float*)d_in[7];
  const float* bk   = (const float*)d_in[8];
  const float* Wv   = (const float*)d_in[9];
  const float* bv   = (const float*)d_in[10];
  const float* Wo   = (const float*)d_in[11];
  const float* bo   = (const float*)d_in[12];
  float* out = (float*)d_out;

  char* ws = (char*)d_ws;
  size_t off = 0;
  auto alloc = [&](size_t bytes) -> void* {
    void* p = (void*)(ws + off);
    off += (bytes + 255) & ~(size_t)255;
    return p;
  };
  u16* Xh   = (u16*)alloc(8192ull * 1024 * 2);
  u16* Xl   = (u16*)alloc(8192ull * 1024 * 2);
  u16* Wfth = (u16*)alloc(512ull * 1024 * 2);
  u16* Wftl = (u16*)alloc(512ull * 1024 * 2);
  u16* Wqth = (u16*)alloc(512ull * 512 * 2);
  u16* Wkth = (u16*)alloc(512ull * 512 * 2);
  u16* Wvth = (u16*)alloc(512ull * 512 * 2);
  u16* Woth = (u16*)alloc(512ull * 512 * 2);
  u16* Fh   = (u16*)alloc(8192ull * 512 * 2);
  u16* Fl   = (u16*)alloc(8192ull * 512 * 2);
  u16* Qh   = (u16*)alloc(8192ull * 512 * 2);
  u16* Kh   = (u16*)alloc(8192ull * 512 * 2);
  u16* Vt   = (u16*)alloc(8192ull * 512 * 2);
  // X is dead after the V projection; attention output aliases it.
  u16* Oh = Xh;

  const float QSC = 0.1803368801f;   // 0.125 * log2(e) — folded into Q, exp via exp2

  split_concat_kernel<<<8192, 256, 0, stream>>>(gene, expr, Xh, Xl);
  transpose_all_kernel<<<384, 256, 0, stream>>>(Wf, Wq, Wk, Wv, Wo,
                                                Wfth, Wftl, Wqth, Wkth, Wvth, Woth);

  // fused = X @ Wf + bf (full split, split output)
  gemm_kernel<3, 0, 0><<<dim3(64, 8), 256, 0, stream>>>(
      Xh, Xl, 1024, Wfth, Wftl, nullptr, 1024, bfv, nullptr, Fh, Fl, nullptr, 1.f, 1.f);
  // Q (pre-scaled) and K in one dual dispatch (A-split x W-hi)
  gemm_kernel<2, 1, 1><<<dim3(64, 16), 256, 0, stream>>>(
      Fh, Fl, 512, Wqth, nullptr, Wkth, 512, bq, bk, Qh, nullptr, Kh, QSC, 1.f);
  // V = expr @ Wv + bv -> bf16 V^T per head (A-split x W-hi)
  gemm_kernel<2, 2, 0><<<dim3(64, 8), 256, 0, stream>>>(
      Xh + 512, Xl + 512, 1024, Wvth, nullptr, nullptr, 512, bv, nullptr, Vt, nullptr, nullptr, 1.f, 1.f);
  // attention: 32x32 core, 2 heads/block, kv-split waves
  flash_kernel<<<dim3(32, 16), 256, 0, stream>>>(Qh, Kh, Vt, Mm, Oh);
  // out = O @ Wo + bo -> f32 (pure bf16)
  gemm_kernel<1, 3, 0><<<dim3(64, 8), 256, 0, stream>>>(
      Oh, nullptr, 512, Woth, nullptr, nullptr, 512, bo, nullptr, out, nullptr, nullptr, 1.f, 1.f);

  (void)in_sizes; (void)n_in; (void)out_size; (void)ws_size;
}